// Round 21
// baseline (312.296 us; speedup 1.0000x reference)
//
#include <hip/hip_runtime.h>
#include <hip/hip_bf16.h>
#include <math.h>

#define N_NODES 50000
#define M_PAD   50048                    // 391 * 128
#define NBLK_GEMM (M_PAD / 128)          // 391
#define N_EDGES 800000
#define F_IN 128
#define HID 64
#define HEADS 4
#define FEAT 256        // HEADS*HID
#define OUT_DIM 128
#define N_CLS 2
#define NG 500
#define SLOPE 0.2f
#define BN_EPS 1e-5f
#define ECAP 64          // ELL slots per node (real edges only; self-loop implicit)
#define EH2 ((N_EDGES + 1) / 2)          // 2 real edges per build thread
#define NBLK_BUILD ((EH2 + 255) / 256)   // 1563

typedef __attribute__((ext_vector_type(8))) short short8;
typedef __attribute__((ext_vector_type(4))) float floatx4;
typedef __attribute__((ext_vector_type(2))) float floatx2;

__device__ inline unsigned short f2bf(float f) {
    unsigned int u = __float_as_uint(f);
    unsigned int lsb = (u >> 16) & 1u;
    return (unsigned short)((u + 0x7fffu + lsb) >> 16);
}

// ==== bf16 MFMA GEMM fused with GAT prologue; full-width 128x256 tile ====
// Carries ELL-build blocks (blockIdx >= NBLK_GEMM) to overlap the
// latency-bound edge scatter with the MFMA GEMM (independent work).
template<bool AF32, bool BUILD>
__global__ __launch_bounds__(256, 2) void gemm_mfma_gat(
    const void* __restrict__ Av, const unsigned short* __restrict__ BT,
    const float* __restrict__ att_src, const float* __restrict__ att_dst,
    unsigned char* __restrict__ h8, float* __restrict__ a_s,
    float* __restrict__ a_d, int K,
    const int* __restrict__ src, const int* __restrict__ dst,
    int* __restrict__ deg, int* __restrict__ ell,
    int* __restrict__ ovf_cnt, int* __restrict__ ovf) {
    constexpr int LS = 40;      // staging row stride (bf16)
    constexpr int C8 = 272;     // fp8 repack row stride (bytes)
    __shared__ __align__(16) unsigned char smem_raw[128 * C8];   // 34816 B
    int t = threadIdx.x;

    if (BUILD && blockIdx.x >= NBLK_GEMM) {
        // ---------- ELL build block: 2 real edges/thread ----------
        int i = (blockIdx.x - NBLK_GEMM) * 256 + t;
        if (i >= EH2) return;
        int ss[2], dd[2], pp[2];
        int nv = 0;
        #pragma unroll
        for (int j = 0; j < 2; j++) {
            int e = i + j * EH2;
            if (e < N_EDGES) { ss[nv] = src[e]; dd[nv] = dst[e]; nv++; }
        }
        #pragma unroll
        for (int j = 0; j < 2; j++)
            if (j < nv) pp[j] = atomicAdd(&deg[dd[j]], 1);
        #pragma unroll
        for (int j = 0; j < 2; j++) {
            if (j >= nv) continue;
            if (pp[j] < ECAP) {
                ell[dd[j] * ECAP + pp[j]] = ss[j];
            } else {
                int k = atomicAdd(ovf_cnt, 1);
                ovf[2 * k] = ss[j];
                ovf[2 * k + 1] = dd[j];
            }
        }
        return;
    }

    // ---------- GEMM block ----------
    unsigned short* As = (unsigned short*)smem_raw;
    unsigned short* Bs = As + 128 * LS;
    unsigned char*  s8 = smem_raw;
    int lane = t & 63, w = t >> 6;
    int row0 = blockIdx.x * 128;
    int mrow = lane & 15, quad = lane >> 4;

    floatx4 acc[8][4] = {};

    int rA = t >> 2, cA = (t & 3) * 8;

    const unsigned short* Ab = (const unsigned short*)Av;
    const float* Af = (const float*)Av;

    for (int k0 = 0; k0 < K; k0 += 32) {
        #pragma unroll
        for (int j = 0; j < 2; j++) {
            int r = rA + j * 64;
            if (AF32) {
                uint4 pk = make_uint4(0, 0, 0, 0);
                if (row0 + r < N_NODES) {
                    float4 f0 = *(const float4*)&Af[(long long)(row0 + r) * K + k0 + cA];
                    float4 f1 = *(const float4*)&Af[(long long)(row0 + r) * K + k0 + cA + 4];
                    pk.x = (unsigned)f2bf(f0.x) | ((unsigned)f2bf(f0.y) << 16);
                    pk.y = (unsigned)f2bf(f0.z) | ((unsigned)f2bf(f0.w) << 16);
                    pk.z = (unsigned)f2bf(f1.x) | ((unsigned)f2bf(f1.y) << 16);
                    pk.w = (unsigned)f2bf(f1.z) | ((unsigned)f2bf(f1.w) << 16);
                }
                *(uint4*)&As[r * LS + cA] = pk;
            } else {
                *(uint4*)&As[r * LS + cA] = *(const uint4*)&Ab[(long long)(row0 + r) * K + k0 + cA];
            }
        }
        #pragma unroll
        for (int j = 0; j < 4; j++) {
            int r = rA + j * 64;
            *(uint4*)&Bs[r * LS + cA] = *(const uint4*)&BT[(long long)r * K + k0 + cA];
        }
        __syncthreads();
        short8 bf[4];
        #pragma unroll
        for (int ni = 0; ni < 4; ni++)
            bf[ni] = *(const short8*)&Bs[(w * 64 + ni * 16 + mrow) * LS + quad * 8];
        #pragma unroll
        for (int mi = 0; mi < 8; mi++) {
            short8 af = *(const short8*)&As[(mi * 16 + mrow) * LS + quad * 8];
            #pragma unroll
            for (int ni = 0; ni < 4; ni++)
                acc[mi][ni] = __builtin_amdgcn_mfma_f32_16x16x32_bf16(af, bf[ni],
                                                                      acc[mi][ni], 0, 0, 0);
        }
        __syncthreads();
    }

    // ---- attention scores (wave w == head w) ----
    float ats[4], atd[4];
    #pragma unroll
    for (int ni = 0; ni < 4; ni++) {
        ats[ni] = att_src[w * 64 + ni * 16 + mrow];
        atd[ni] = att_dst[w * 64 + ni * 16 + mrow];
    }
    #pragma unroll
    for (int mi = 0; mi < 8; mi++) {
        #pragma unroll
        for (int r = 0; r < 4; r++) {
            int row = row0 + mi * 16 + quad * 4 + r;
            float ps = 0.f, pd = 0.f;
            #pragma unroll
            for (int ni = 0; ni < 4; ni++) {
                float v = acc[mi][ni][r];
                ps += v * ats[ni];
                pd += v * atd[ni];
            }
            #pragma unroll
            for (int off = 1; off < 16; off <<= 1) {
                ps += __shfl_xor(ps, off);
                pd += __shfl_xor(pd, off);
            }
            if (mrow == 0 && row < N_NODES) {
                a_s[row * 4 + w] = ps;
                a_d[row * 4 + w] = pd;
            }
        }
    }

    // ---- repack C tile as fp8 through LDS, coalesced uint4 stores ----
    #pragma unroll
    for (int mi = 0; mi < 8; mi++)
        #pragma unroll
        for (int r = 0; r < 4; r++) {
            int row = mi * 16 + quad * 4 + r;
            #pragma unroll
            for (int ni = 0; ni < 4; ni += 2) {
                int pk = __builtin_amdgcn_cvt_pk_fp8_f32(acc[mi][ni][r],
                                                         acc[mi][ni + 1][r], 0, false);
                s8[row * C8 + w * 64 + ni * 16 + mrow]       = (unsigned char)(pk & 0xff);
                s8[row * C8 + w * 64 + (ni + 1) * 16 + mrow] = (unsigned char)((pk >> 8) & 0xff);
            }
        }
    __syncthreads();
    {
        int r2 = t >> 1, half = t & 1;
        const uint4* sp = (const uint4*)&s8[r2 * C8 + half * 128];
        uint4* dp = (uint4*)&h8[(long long)(row0 + r2) * FEAT + half * 128];
        #pragma unroll
        for (int k = 0; k < 8; k++)
            dp[k] = sp[k];
    }
}

// ===== prep: weight transposes + deg/ovf zero + h1bf pad zero =====
__global__ void prep(const float* __restrict__ W1, const float* __restrict__ W2,
                     unsigned short* __restrict__ W1T, unsigned short* __restrict__ W2T,
                     int* __restrict__ deg, int* __restrict__ ovf_cnt,
                     unsigned long long* __restrict__ h1bf_pad) {
    int i = blockIdx.x * 256 + threadIdx.x;
    if (i < F_IN * 256) {
        int k = i >> 8, n = i & 255;
        W1T[n * F_IN + k] = f2bf(W1[i]);
    }
    int j = i - F_IN * 256;
    if (j >= 0 && j < FEAT * 256) {
        int k = j >> 8, n = j & 255;
        W2T[n * FEAT + k] = f2bf(W2[j]);
    }
    if (i < N_NODES) deg[i] = 0;          // self-loop NOT stored (implicit)
    if (i == 0) *ovf_cnt = 0;
    if (i < (M_PAD - N_NODES) * FEAT / 4) h1bf_pad[i] = 0ULL;
}

// ===== fused GAT, wave-per-node; fp8 gather from ELL; implicit self-loop =====
// shared-max softmax (exact), in-loop denominator, bf16 output.
__global__ __launch_bounds__(256) void gat_fused(
    const int* __restrict__ deg_arr, const int* __restrict__ ell,
    const int* __restrict__ ovf_cnt, const int* __restrict__ ovf,
    const float* __restrict__ a_s, const float* __restrict__ a_d,
    const unsigned char* __restrict__ h8, const float* __restrict__ bias,
    const float* __restrict__ g, const float* __restrict__ be,
    const float* __restrict__ rm, const float* __restrict__ rv,
    unsigned short* __restrict__ out16) {
    int t = threadIdx.x;
    int lane = t & 63;
    int w = t >> 6;
    int hd = lane >> 4;
    int d = blockIdx.x * 4 + w;

    __shared__ float p_lds[4 * ECAP * 4];
    __shared__ int   o_lds[4 * ECAP];
    float* pw = &p_lds[w * ECAP * 4];
    int*   ow = &o_lds[w * ECAP];

    const unsigned int* __restrict__ H1 = (const unsigned int*)h8;

    int deg = deg_arr[d];                 // real edges only
    float4 ad4 = *(const float4*)&a_d[d * 4];
    float4 asd = *(const float4*)&a_s[d * 4];
    // self-loop logits (uniform across lanes)
    float lgS[4];
    {
        float e0 = asd.x + ad4.x; lgS[0] = e0 > 0.f ? e0 : SLOPE * e0;
        float e1 = asd.y + ad4.y; lgS[1] = e1 > 0.f ? e1 : SLOPE * e1;
        float e2 = asd.z + ad4.z; lgS[2] = e2 > 0.f ? e2 : SLOPE * e2;
        float e3 = asd.w + ad4.w; lgS[3] = e3 > 0.f ? e3 : SLOPE * e3;
    }
    float lgSmax = fmaxf(fmaxf(lgS[0], lgS[1]), fmaxf(lgS[2], lgS[3]));

    float den = 0.f;
    float4 acc = make_float4(0.f, 0.f, 0.f, 0.f);

    if (deg <= ECAP) {
        float lg[4] = {-INFINITY, -INFINITY, -INFINITY, -INFINITY};
        if (lane < deg) {
            int s = ell[d * ECAP + lane];
            ow[lane] = s * 64;
            float4 as4 = *(const float4*)&a_s[s * 4];
            float e0 = as4.x + ad4.x; lg[0] = e0 > 0.f ? e0 : SLOPE * e0;
            float e1 = as4.y + ad4.y; lg[1] = e1 > 0.f ? e1 : SLOPE * e1;
            float e2 = as4.z + ad4.z; lg[2] = e2 > 0.f ? e2 : SLOPE * e2;
            float e3 = as4.w + ad4.w; lg[3] = e3 > 0.f ? e3 : SLOPE * e3;
        }
        float mm = fmaxf(fmaxf(lg[0], lg[1]), fmaxf(lg[2], lg[3]));
        mm = fmaxf(mm, lgSmax);
        #pragma unroll
        for (int off = 1; off < 64; off <<= 1) mm = fmaxf(mm, __shfl_xor(mm, off));
        if (lane < deg) {
            float4 pq;
            pq.x = __expf(lg[0] - mm);
            pq.y = __expf(lg[1] - mm);
            pq.z = __expf(lg[2] - mm);
            pq.w = __expf(lg[3] - mm);
            *(float4*)&pw[lane * 4] = pq;
        }
        // self-loop contribution (uniform row load, coalesced)
        {
            float pS = __expf(lgS[hd] - mm);
            int uS = (int)H1[d * 64 + lane];
            den += pS;
            floatx2 s0 = __builtin_amdgcn_cvt_pk_f32_fp8(uS, false);
            floatx2 s1 = __builtin_amdgcn_cvt_pk_f32_fp8(uS, true);
            acc.x += pS * s0.x; acc.y += pS * s0.y;
            acc.z += pS * s1.x; acc.w += pS * s1.y;
        }
        int e = 0;
        for (; e + 1 < deg; e += 2) {
            int oA = ow[e], oB = ow[e + 1];
            float pA = pw[e * 4 + hd], pB = pw[(e + 1) * 4 + hd];
            int uA = (int)H1[oA + lane];
            int uB = (int)H1[oB + lane];
            den += pA + pB;
            floatx2 a0 = __builtin_amdgcn_cvt_pk_f32_fp8(uA, false);
            floatx2 a1 = __builtin_amdgcn_cvt_pk_f32_fp8(uA, true);
            floatx2 b0 = __builtin_amdgcn_cvt_pk_f32_fp8(uB, false);
            floatx2 b1 = __builtin_amdgcn_cvt_pk_f32_fp8(uB, true);
            acc.x += pA * a0.x; acc.y += pA * a0.y;
            acc.z += pA * a1.x; acc.w += pA * a1.y;
            acc.x += pB * b0.x; acc.y += pB * b0.y;
            acc.z += pB * b1.x; acc.w += pB * b1.y;
        }
        if (e < deg) {
            int oA = ow[e];
            float pA = pw[e * 4 + hd];
            int uA = (int)H1[oA + lane];
            den += pA;
            floatx2 a0 = __builtin_amdgcn_cvt_pk_f32_fp8(uA, false);
            floatx2 a1 = __builtin_amdgcn_cvt_pk_f32_fp8(uA, true);
            acc.x += pA * a0.x; acc.y += pA * a0.y;
            acc.z += pA * a1.x; acc.w += pA * a1.y;
        }
    } else {
        // exact online path: self-loop + ELL chunk + overflow scan
        float m_old;
        {
            int s = ell[d * ECAP + lane];
            ow[lane] = s * 64;
            float4 as4 = *(const float4*)&a_s[s * 4];
            float lg[4];
            float e0 = as4.x + ad4.x; lg[0] = e0 > 0.f ? e0 : SLOPE * e0;
            float e1 = as4.y + ad4.y; lg[1] = e1 > 0.f ? e1 : SLOPE * e1;
            float e2 = as4.z + ad4.z; lg[2] = e2 > 0.f ? e2 : SLOPE * e2;
            float e3 = as4.w + ad4.w; lg[3] = e3 > 0.f ? e3 : SLOPE * e3;
            float mm = fmaxf(fmaxf(lg[0], lg[1]), fmaxf(lg[2], lg[3]));
            mm = fmaxf(mm, lgSmax);
            #pragma unroll
            for (int off = 1; off < 64; off <<= 1) mm = fmaxf(mm, __shfl_xor(mm, off));
            m_old = mm;
            float4 pq;
            pq.x = __expf(lg[0] - mm);
            pq.y = __expf(lg[1] - mm);
            pq.z = __expf(lg[2] - mm);
            pq.w = __expf(lg[3] - mm);
            *(float4*)&pw[lane * 4] = pq;
            // self-loop
            float pS = __expf(lgS[hd] - mm);
            int uS = (int)H1[d * 64 + lane];
            den += pS;
            floatx2 s0 = __builtin_amdgcn_cvt_pk_f32_fp8(uS, false);
            floatx2 s1 = __builtin_amdgcn_cvt_pk_f32_fp8(uS, true);
            acc.x += pS * s0.x; acc.y += pS * s0.y;
            acc.z += pS * s1.x; acc.w += pS * s1.y;
            for (int e = 0; e < ECAP; e++) {
                int oA = ow[e];
                float pA = pw[e * 4 + hd];
                int uA = (int)H1[oA + lane];
                den += pA;
                floatx2 a0 = __builtin_amdgcn_cvt_pk_f32_fp8(uA, false);
                floatx2 a1 = __builtin_amdgcn_cvt_pk_f32_fp8(uA, true);
                acc.x += pA * a0.x; acc.y += pA * a0.y;
                acc.z += pA * a1.x; acc.w += pA * a1.y;
            }
        }
        int nov = *ovf_cnt;
        for (int i = 0; i < nov; i++) {
            int s2 = ovf[2 * i], d2 = ovf[2 * i + 1];
            if (d2 != d) continue;
            float4 as4 = *(const float4*)&a_s[s2 * 4];
            float lg[4];
            float e0 = as4.x + ad4.x; lg[0] = e0 > 0.f ? e0 : SLOPE * e0;
            float e1 = as4.y + ad4.y; lg[1] = e1 > 0.f ? e1 : SLOPE * e1;
            float e2 = as4.z + ad4.z; lg[2] = e2 > 0.f ? e2 : SLOPE * e2;
            float e3 = as4.w + ad4.w; lg[3] = e3 > 0.f ? e3 : SLOPE * e3;
            float mmax = fmaxf(fmaxf(lg[0], lg[1]), fmaxf(lg[2], lg[3]));
            float m_new = fmaxf(m_old, mmax);
            float alpha = __expf(m_old - m_new);
            m_old = m_new;
            float ph = __expf(lg[hd] - m_new);
            acc.x *= alpha; acc.y *= alpha; acc.z *= alpha; acc.w *= alpha;
            den = den * alpha + ph;
            int u = (int)H1[s2 * 64 + lane];
            floatx2 a0 = __builtin_amdgcn_cvt_pk_f32_fp8(u, false);
            floatx2 a1 = __builtin_amdgcn_cvt_pk_f32_fp8(u, true);
            acc.x += ph * a0.x; acc.y += ph * a0.y;
            acc.z += ph * a1.x; acc.w += ph * a1.y;
        }
    }
    float inv = 1.f / den;
    int c0 = lane * 4;
    float4 bi = *(const float4*)&bias[c0];
    float4 gg = *(const float4*)&g[c0];
    float4 bb = *(const float4*)&be[c0];
    float4 mm4 = *(const float4*)&rm[c0];
    float4 vv = *(const float4*)&rv[c0];
    float v0 = fmaxf(acc.x * inv + bi.x, 0.f);
    float v1 = fmaxf(acc.y * inv + bi.y, 0.f);
    float v2 = fmaxf(acc.z * inv + bi.z, 0.f);
    float v3 = fmaxf(acc.w * inv + bi.w, 0.f);
    v0 = (v0 - mm4.x) * rsqrtf(vv.x + BN_EPS) * gg.x + bb.x;
    v1 = (v1 - mm4.y) * rsqrtf(vv.y + BN_EPS) * gg.y + bb.y;
    v2 = (v2 - mm4.z) * rsqrtf(vv.z + BN_EPS) * gg.z + bb.z;
    v3 = (v3 - mm4.w) * rsqrtf(vv.w + BN_EPS) * gg.w + bb.w;
    unsigned long long o =
        (unsigned long long)f2bf(v0) |
        ((unsigned long long)f2bf(v1) << 16) |
        ((unsigned long long)f2bf(v2) << 32) |
        ((unsigned long long)f2bf(v3) << 48);
    __builtin_nontemporal_store(o, (unsigned long long*)&out16[(long long)d * FEAT + c0]);
}

// ===== fused head: mean-pool bf16 h2 + relu(pooled@lw1+lb1) @ lw2 + lb2 =====
__global__ __launch_bounds__(256) void head_fused(
    const unsigned short* __restrict__ h2, const int* __restrict__ batch,
    const float* __restrict__ lw1, const float* __restrict__ lb1,
    const float* __restrict__ lw2, const float* __restrict__ lb2,
    float* __restrict__ out) {
    int gph = blockIdx.x;
    int t = threadIdx.x;
    __shared__ float pooled[FEAT];
    __shared__ float zl[OUT_DIM];
    __shared__ int lo_s, hi_s;
    if (t == 0) {
        int lo = 0, hi = N_NODES;
        while (lo < hi) { int mid = (lo + hi) >> 1; if (batch[mid] < gph) lo = mid + 1; else hi = mid; }
        lo_s = lo;
        int lo2 = 0, hi2 = N_NODES;
        while (lo2 < hi2) { int mid = (lo2 + hi2) >> 1; if (batch[mid] < gph + 1) lo2 = mid + 1; else hi2 = mid; }
        hi_s = lo2;
    }
    __syncthreads();
    int lo = lo_s, hi = hi_s;
    float a0 = 0.f, a1 = 0.f, a2 = 0.f, a3 = 0.f;
    int n = lo;
    for (; n + 3 < hi; n += 4) {
        a0 += __uint_as_float((unsigned)h2[(long long)n * FEAT + t] << 16);
        a1 += __uint_as_float((unsigned)h2[(long long)(n + 1) * FEAT + t] << 16);
        a2 += __uint_as_float((unsigned)h2[(long long)(n + 2) * FEAT + t] << 16);
        a3 += __uint_as_float((unsigned)h2[(long long)(n + 3) * FEAT + t] << 16);
    }
    for (; n < hi; n++) a0 += __uint_as_float((unsigned)h2[(long long)n * FEAT + t] << 16);
    float cnt = fmaxf((float)(hi - lo), 1.f);
    pooled[t] = (a0 + a1 + a2 + a3) / cnt;
    __syncthreads();
    int j = t >> 1, kh = t & 1;
    float zp = 0.f;
    #pragma unroll 8
    for (int k = kh * 128; k < kh * 128 + 128; k++)
        zp += pooled[k] * lw1[k * OUT_DIM + j];
    zp += __shfl_xor(zp, 1);
    if (kh == 0) zl[j] = fmaxf(zp + lb1[j], 0.f);
    __syncthreads();
    int w = t >> 6, lane = t & 63;
    if (w < 2) {
        float p = zl[lane] * lw2[lane * 2 + w] + zl[lane + 64] * lw2[(lane + 64) * 2 + w];
        #pragma unroll
        for (int off = 1; off < 64; off <<= 1) p += __shfl_xor(p, off);
        if (lane == 0) out[gph * 2 + w] = p + lb2[w];
    }
}

extern "C" void kernel_launch(void* const* d_in, const int* in_sizes, int n_in,
                              void* d_out, int out_size, void* d_ws, size_t ws_size,
                              hipStream_t stream) {
    const float* x       = (const float*)d_in[0];
    const int*   ei      = (const int*)d_in[1];
    const int*   batch   = (const int*)d_in[2];
    const float* W1      = (const float*)d_in[3];
    const float* att_s1  = (const float*)d_in[4];
    const float* att_d1  = (const float*)d_in[5];
    const float* b1      = (const float*)d_in[6];
    const float* g1      = (const float*)d_in[7];
    const float* be1     = (const float*)d_in[8];
    const float* rm1     = (const float*)d_in[9];
    const float* rv1     = (const float*)d_in[10];
    const float* W2      = (const float*)d_in[11];
    const float* att_s2  = (const float*)d_in[12];
    const float* att_d2  = (const float*)d_in[13];
    const float* b2      = (const float*)d_in[14];
    const float* g2      = (const float*)d_in[15];
    const float* be2     = (const float*)d_in[16];
    const float* rm2     = (const float*)d_in[17];
    const float* rv2     = (const float*)d_in[18];
    const float* lw1     = (const float*)d_in[19];
    const float* lb1     = (const float*)d_in[20];
    const float* lw2     = (const float*)d_in[21];
    const float* lb2     = (const float*)d_in[22];
    float* out           = (float*)d_out;

    const int* src = ei;
    const int* dst = ei + N_EDGES;

    char* p = (char*)d_ws;
    auto carve = [&p](size_t bytes) -> void* {
        void* r = (void*)p;
        p += (bytes + 63) & ~(size_t)63;
        return r;
    };
    unsigned short* h2bf = (unsigned short*)carve(sizeof(short) * (size_t)N_NODES * FEAT);
    float* a_s    = (float*)carve(sizeof(float) * N_NODES * HEADS);
    float* a_d    = (float*)carve(sizeof(float) * N_NODES * HEADS);
    int*   deg    = (int*)carve(sizeof(int) * N_NODES);
    int*   ell    = (int*)carve(sizeof(int) * (size_t)N_NODES * ECAP);
    int*   ovf_cnt= (int*)carve(sizeof(int) * 16);
    int*   ovf    = (int*)carve(sizeof(int) * 2 * N_EDGES);
    unsigned char*  h8   = (unsigned char*)carve((size_t)M_PAD * FEAT);
    unsigned short* h1bf = (unsigned short*)carve(sizeof(short) * (size_t)M_PAD * FEAT);
    unsigned short* w1t  = (unsigned short*)carve(sizeof(short) * FEAT * F_IN);
    unsigned short* w2t  = (unsigned short*)carve(sizeof(short) * FEAT * FEAT);

    // ---- prep: weight transposes + deg/ovf zero + pad zero ----
    prep<<<((F_IN + FEAT) * 256 + 255) / 256, 256, 0, stream>>>(
        W1, W2, w1t, w2t, deg, ovf_cnt,
        (unsigned long long*)(h1bf + (size_t)N_NODES * FEAT));

    // ---- Layer 1 GEMM + ELL build in one heterogeneous launch ----
    gemm_mfma_gat<true, true><<<NBLK_GEMM + NBLK_BUILD, 256, 0, stream>>>(
        x, w1t, att_s1, att_d1, h8, a_s, a_d, F_IN,
        src, dst, deg, ell, ovf_cnt, ovf);
    gat_fused<<<N_NODES / 4, 256, 0, stream>>>(deg, ell, ovf_cnt, ovf, a_s, a_d, h8,
                                               b1, g1, be1, rm1, rv1, h1bf);

    // ---- Layer 2 ----
    gemm_mfma_gat<false, false><<<NBLK_GEMM, 256, 0, stream>>>(
        h1bf, w2t, att_s2, att_d2, h8, a_s, a_d, FEAT,
        nullptr, nullptr, nullptr, nullptr, nullptr, nullptr);
    gat_fused<<<N_NODES / 4, 256, 0, stream>>>(deg, ell, ovf_cnt, ovf, a_s, a_d, h8,
                                               b2, g2, be2, rm2, rv2, h2bf);

    // ---- fused head ----
    head_fused<<<NG, 256, 0, stream>>>(h2bf, batch, lw1, lb1, lw2, lb2, out);
}

// Round 22
// 307.795 us; speedup vs baseline: 1.0146x; 1.0146x over previous
//
#include <hip/hip_runtime.h>
#include <hip/hip_bf16.h>
#include <math.h>

#define N_NODES 50000
#define M_PAD   50048                    // 391 * 128
#define NBLK_GEMM (M_PAD / 128)          // 391
#define N_EDGES 800000
#define F_IN 128
#define HID 64
#define HEADS 4
#define FEAT 256        // HEADS*HID
#define OUT_DIM 128
#define N_CLS 2
#define NG 500
#define SLOPE 0.2f
#define BN_EPS 1e-5f
#define ECAP 64          // ELL slots per node (Poisson(17) -> overflow ~never)
#define ET (N_EDGES + N_NODES)
#define EH ((ET + 1) / 2)                // 2 edges per thread in build
#define NBLK_BUILD ((EH + 255) / 256)    // 1661

typedef __attribute__((ext_vector_type(8))) short short8;
typedef __attribute__((ext_vector_type(4))) float floatx4;
typedef __attribute__((ext_vector_type(2))) float floatx2;

__device__ inline unsigned short f2bf(float f) {
    unsigned int u = __float_as_uint(f);
    unsigned int lsb = (u >> 16) & 1u;
    return (unsigned short)((u + 0x7fffu + lsb) >> 16);
}

// ==== bf16 MFMA GEMM fused with GAT prologue; full-width 128x256 tile ====
// Optionally carries ELL-build blocks (blockIdx >= NBLK_GEMM) to overlap the
// latency-bound edge scatter with the MFMA GEMM (independent work).
template<bool AF32, bool BUILD>
__global__ __launch_bounds__(256, 2) void gemm_mfma_gat(
    const void* __restrict__ Av, const unsigned short* __restrict__ BT,
    const float* __restrict__ att_src, const float* __restrict__ att_dst,
    unsigned char* __restrict__ h8, float* __restrict__ a_s,
    float* __restrict__ a_d, int K,
    const int* __restrict__ src, const int* __restrict__ dst,
    int* __restrict__ deg, int* __restrict__ ell,
    int* __restrict__ ovf_cnt, int* __restrict__ ovf) {
    constexpr int LS = 40;      // staging row stride (bf16)
    constexpr int C8 = 272;     // fp8 repack row stride (bytes)
    __shared__ __align__(16) unsigned char smem_raw[128 * C8];   // 34816 B
    int t = threadIdx.x;

    if (BUILD && blockIdx.x >= NBLK_GEMM) {
        // ---------- ELL build block: 2 edges/thread ----------
        int i = (blockIdx.x - NBLK_GEMM) * 256 + t;
        if (i >= EH) return;
        int ss[2], dd[2], pp[2];
        int nv = 0;
        #pragma unroll
        for (int j = 0; j < 2; j++) {
            int e = i + j * EH;
            if (e < ET) {
                if (e < N_EDGES) { ss[nv] = src[e]; dd[nv] = dst[e]; }
                else             { ss[nv] = dd[nv] = e - N_EDGES; }
                nv++;
            }
        }
        #pragma unroll
        for (int j = 0; j < 2; j++)
            if (j < nv) pp[j] = atomicAdd(&deg[dd[j]], 1);
        #pragma unroll
        for (int j = 0; j < 2; j++) {
            if (j >= nv) continue;
            if (pp[j] < ECAP) {
                ell[dd[j] * ECAP + pp[j]] = ss[j];
            } else {
                int k = atomicAdd(ovf_cnt, 1);
                ovf[2 * k] = ss[j];
                ovf[2 * k + 1] = dd[j];
            }
        }
        return;
    }

    // ---------- GEMM block ----------
    unsigned short* As = (unsigned short*)smem_raw;
    unsigned short* Bs = As + 128 * LS;
    unsigned char*  s8 = smem_raw;
    int lane = t & 63, w = t >> 6;
    int row0 = blockIdx.x * 128;
    int mrow = lane & 15, quad = lane >> 4;

    floatx4 acc[8][4] = {};

    int rA = t >> 2, cA = (t & 3) * 8;

    const unsigned short* Ab = (const unsigned short*)Av;
    const float* Af = (const float*)Av;

    for (int k0 = 0; k0 < K; k0 += 32) {
        #pragma unroll
        for (int j = 0; j < 2; j++) {
            int r = rA + j * 64;
            if (AF32) {
                uint4 pk = make_uint4(0, 0, 0, 0);
                if (row0 + r < N_NODES) {
                    float4 f0 = *(const float4*)&Af[(long long)(row0 + r) * K + k0 + cA];
                    float4 f1 = *(const float4*)&Af[(long long)(row0 + r) * K + k0 + cA + 4];
                    pk.x = (unsigned)f2bf(f0.x) | ((unsigned)f2bf(f0.y) << 16);
                    pk.y = (unsigned)f2bf(f0.z) | ((unsigned)f2bf(f0.w) << 16);
                    pk.z = (unsigned)f2bf(f1.x) | ((unsigned)f2bf(f1.y) << 16);
                    pk.w = (unsigned)f2bf(f1.z) | ((unsigned)f2bf(f1.w) << 16);
                }
                *(uint4*)&As[r * LS + cA] = pk;
            } else {
                *(uint4*)&As[r * LS + cA] = *(const uint4*)&Ab[(long long)(row0 + r) * K + k0 + cA];
            }
        }
        #pragma unroll
        for (int j = 0; j < 4; j++) {
            int r = rA + j * 64;
            *(uint4*)&Bs[r * LS + cA] = *(const uint4*)&BT[(long long)r * K + k0 + cA];
        }
        __syncthreads();
        short8 bf[4];
        #pragma unroll
        for (int ni = 0; ni < 4; ni++)
            bf[ni] = *(const short8*)&Bs[(w * 64 + ni * 16 + mrow) * LS + quad * 8];
        #pragma unroll
        for (int mi = 0; mi < 8; mi++) {
            short8 af = *(const short8*)&As[(mi * 16 + mrow) * LS + quad * 8];
            #pragma unroll
            for (int ni = 0; ni < 4; ni++)
                acc[mi][ni] = __builtin_amdgcn_mfma_f32_16x16x32_bf16(af, bf[ni],
                                                                      acc[mi][ni], 0, 0, 0);
        }
        __syncthreads();
    }

    // ---- attention scores (wave w == head w) ----
    float ats[4], atd[4];
    #pragma unroll
    for (int ni = 0; ni < 4; ni++) {
        ats[ni] = att_src[w * 64 + ni * 16 + mrow];
        atd[ni] = att_dst[w * 64 + ni * 16 + mrow];
    }
    #pragma unroll
    for (int mi = 0; mi < 8; mi++) {
        #pragma unroll
        for (int r = 0; r < 4; r++) {
            int row = row0 + mi * 16 + quad * 4 + r;
            float ps = 0.f, pd = 0.f;
            #pragma unroll
            for (int ni = 0; ni < 4; ni++) {
                float v = acc[mi][ni][r];
                ps += v * ats[ni];
                pd += v * atd[ni];
            }
            #pragma unroll
            for (int off = 1; off < 16; off <<= 1) {
                ps += __shfl_xor(ps, off);
                pd += __shfl_xor(pd, off);
            }
            if (mrow == 0 && row < N_NODES) {
                a_s[row * 4 + w] = ps;
                a_d[row * 4 + w] = pd;
            }
        }
    }

    // ---- repack C tile as fp8 through LDS, coalesced uint4 stores ----
    #pragma unroll
    for (int mi = 0; mi < 8; mi++)
        #pragma unroll
        for (int r = 0; r < 4; r++) {
            int row = mi * 16 + quad * 4 + r;
            #pragma unroll
            for (int ni = 0; ni < 4; ni += 2) {
                int pk = __builtin_amdgcn_cvt_pk_fp8_f32(acc[mi][ni][r],
                                                         acc[mi][ni + 1][r], 0, false);
                s8[row * C8 + w * 64 + ni * 16 + mrow]       = (unsigned char)(pk & 0xff);
                s8[row * C8 + w * 64 + (ni + 1) * 16 + mrow] = (unsigned char)((pk >> 8) & 0xff);
            }
        }
    __syncthreads();
    {
        int r2 = t >> 1, half = t & 1;
        const uint4* sp = (const uint4*)&s8[r2 * C8 + half * 128];
        uint4* dp = (uint4*)&h8[(long long)(row0 + r2) * FEAT + half * 128];
        #pragma unroll
        for (int k = 0; k < 8; k++)
            dp[k] = sp[k];
    }
}

// ===== prep: weight transposes + deg zero + ovf_cnt zero + h1bf pad zero =====
__global__ void prep(const float* __restrict__ W1, const float* __restrict__ W2,
                     unsigned short* __restrict__ W1T, unsigned short* __restrict__ W2T,
                     int* __restrict__ deg, int* __restrict__ ovf_cnt,
                     unsigned long long* __restrict__ h1bf_pad) {
    int i = blockIdx.x * 256 + threadIdx.x;
    if (i < F_IN * 256) {
        int k = i >> 8, n = i & 255;
        W1T[n * F_IN + k] = f2bf(W1[i]);
    }
    int j = i - F_IN * 256;
    if (j >= 0 && j < FEAT * 256) {
        int k = j >> 8, n = j & 255;
        W2T[n * FEAT + k] = f2bf(W2[j]);
    }
    if (i < N_NODES) deg[i] = 0;
    if (i == 0) *ovf_cnt = 0;
    if (i < (M_PAD - N_NODES) * FEAT / 4) h1bf_pad[i] = 0ULL;
}

// ===== fused GAT, wave-per-node; fp8 gather from ELL, packed decode =====
__global__ __launch_bounds__(256) void gat_fused(
    const int* __restrict__ deg_arr, const int* __restrict__ ell,
    const int* __restrict__ ovf_cnt, const int* __restrict__ ovf,
    const float* __restrict__ a_s, const float* __restrict__ a_d,
    const unsigned char* __restrict__ h8, const float* __restrict__ bias,
    const float* __restrict__ g, const float* __restrict__ be,
    const float* __restrict__ rm, const float* __restrict__ rv,
    unsigned short* __restrict__ out16) {
    int t = threadIdx.x;
    int lane = t & 63;
    int w = t >> 6;
    int hd = lane >> 4;
    int d = blockIdx.x * 4 + w;

    __shared__ float p_lds[4 * ECAP * 4];
    __shared__ int   o_lds[4 * ECAP];
    float* pw = &p_lds[w * ECAP * 4];
    int*   ow = &o_lds[w * ECAP];

    const unsigned int* __restrict__ H1 = (const unsigned int*)h8;

    int deg = deg_arr[d];
    float4 ad4 = *(const float4*)&a_d[d * 4];

    float den = 0.f;
    float4 acc = make_float4(0.f, 0.f, 0.f, 0.f);

    if (deg <= ECAP) {
        float lg[4] = {-INFINITY, -INFINITY, -INFINITY, -INFINITY};
        if (lane < deg) {
            int s = ell[d * ECAP + lane];
            ow[lane] = s * 64;
            float4 as4 = *(const float4*)&a_s[s * 4];
            float e0 = as4.x + ad4.x; lg[0] = e0 > 0.f ? e0 : SLOPE * e0;
            float e1 = as4.y + ad4.y; lg[1] = e1 > 0.f ? e1 : SLOPE * e1;
            float e2 = as4.z + ad4.z; lg[2] = e2 > 0.f ? e2 : SLOPE * e2;
            float e3 = as4.w + ad4.w; lg[3] = e3 > 0.f ? e3 : SLOPE * e3;
        }
        float mm = fmaxf(fmaxf(lg[0], lg[1]), fmaxf(lg[2], lg[3]));
        #pragma unroll
        for (int off = 1; off < 64; off <<= 1) mm = fmaxf(mm, __shfl_xor(mm, off));
        if (lane < deg) {
            float4 pq;
            pq.x = __expf(lg[0] - mm);
            pq.y = __expf(lg[1] - mm);
            pq.z = __expf(lg[2] - mm);
            pq.w = __expf(lg[3] - mm);
            *(float4*)&pw[lane * 4] = pq;
        }
        int e = 0;
        for (; e + 1 < deg; e += 2) {
            int oA = ow[e], oB = ow[e + 1];
            float pA = pw[e * 4 + hd], pB = pw[(e + 1) * 4 + hd];
            int uA = (int)H1[oA + lane];
            int uB = (int)H1[oB + lane];
            den += pA + pB;
            floatx2 a0 = __builtin_amdgcn_cvt_pk_f32_fp8(uA, false);
            floatx2 a1 = __builtin_amdgcn_cvt_pk_f32_fp8(uA, true);
            floatx2 b0 = __builtin_amdgcn_cvt_pk_f32_fp8(uB, false);
            floatx2 b1 = __builtin_amdgcn_cvt_pk_f32_fp8(uB, true);
            acc.x += pA * a0.x; acc.y += pA * a0.y;
            acc.z += pA * a1.x; acc.w += pA * a1.y;
            acc.x += pB * b0.x; acc.y += pB * b0.y;
            acc.z += pB * b1.x; acc.w += pB * b1.y;
        }
        if (e < deg) {
            int oA = ow[e];
            float pA = pw[e * 4 + hd];
            int uA = (int)H1[oA + lane];
            den += pA;
            floatx2 a0 = __builtin_amdgcn_cvt_pk_f32_fp8(uA, false);
            floatx2 a1 = __builtin_amdgcn_cvt_pk_f32_fp8(uA, true);
            acc.x += pA * a0.x; acc.y += pA * a0.y;
            acc.z += pA * a1.x; acc.w += pA * a1.y;
        }
    } else {
        // exact online path: ELL chunk (ECAP edges) + overflow scan
        float m_old;
        {
            int s = ell[d * ECAP + lane];
            ow[lane] = s * 64;
            float4 as4 = *(const float4*)&a_s[s * 4];
            float lg[4];
            float e0 = as4.x + ad4.x; lg[0] = e0 > 0.f ? e0 : SLOPE * e0;
            float e1 = as4.y + ad4.y; lg[1] = e1 > 0.f ? e1 : SLOPE * e1;
            float e2 = as4.z + ad4.z; lg[2] = e2 > 0.f ? e2 : SLOPE * e2;
            float e3 = as4.w + ad4.w; lg[3] = e3 > 0.f ? e3 : SLOPE * e3;
            float mm = fmaxf(fmaxf(lg[0], lg[1]), fmaxf(lg[2], lg[3]));
            #pragma unroll
            for (int off = 1; off < 64; off <<= 1) mm = fmaxf(mm, __shfl_xor(mm, off));
            m_old = mm;
            float4 pq;
            pq.x = __expf(lg[0] - mm);
            pq.y = __expf(lg[1] - mm);
            pq.z = __expf(lg[2] - mm);
            pq.w = __expf(lg[3] - mm);
            *(float4*)&pw[lane * 4] = pq;
            for (int e = 0; e < ECAP; e++) {
                int oA = ow[e];
                float pA = pw[e * 4 + hd];
                int uA = (int)H1[oA + lane];
                den += pA;
                floatx2 a0 = __builtin_amdgcn_cvt_pk_f32_fp8(uA, false);
                floatx2 a1 = __builtin_amdgcn_cvt_pk_f32_fp8(uA, true);
                acc.x += pA * a0.x; acc.y += pA * a0.y;
                acc.z += pA * a1.x; acc.w += pA * a1.y;
            }
        }
        int nov = *ovf_cnt;
        for (int i = 0; i < nov; i++) {
            int s2 = ovf[2 * i], d2 = ovf[2 * i + 1];
            if (d2 != d) continue;
            float4 as4 = *(const float4*)&a_s[s2 * 4];
            float lg[4];
            float e0 = as4.x + ad4.x; lg[0] = e0 > 0.f ? e0 : SLOPE * e0;
            float e1 = as4.y + ad4.y; lg[1] = e1 > 0.f ? e1 : SLOPE * e1;
            float e2 = as4.z + ad4.z; lg[2] = e2 > 0.f ? e2 : SLOPE * e2;
            float e3 = as4.w + ad4.w; lg[3] = e3 > 0.f ? e3 : SLOPE * e3;
            float mmax = fmaxf(fmaxf(lg[0], lg[1]), fmaxf(lg[2], lg[3]));
            float m_new = fmaxf(m_old, mmax);
            float alpha = __expf(m_old - m_new);
            m_old = m_new;
            float ph = __expf(lg[hd] - m_new);
            acc.x *= alpha; acc.y *= alpha; acc.z *= alpha; acc.w *= alpha;
            den = den * alpha + ph;
            int u = (int)H1[s2 * 64 + lane];
            floatx2 a0 = __builtin_amdgcn_cvt_pk_f32_fp8(u, false);
            floatx2 a1 = __builtin_amdgcn_cvt_pk_f32_fp8(u, true);
            acc.x += ph * a0.x; acc.y += ph * a0.y;
            acc.z += ph * a1.x; acc.w += ph * a1.y;
        }
    }
    float inv = 1.f / den;
    int c0 = lane * 4;
    float4 bi = *(const float4*)&bias[c0];
    float4 gg = *(const float4*)&g[c0];
    float4 bb = *(const float4*)&be[c0];
    float4 mm4 = *(const float4*)&rm[c0];
    float4 vv = *(const float4*)&rv[c0];
    float v0 = fmaxf(acc.x * inv + bi.x, 0.f);
    float v1 = fmaxf(acc.y * inv + bi.y, 0.f);
    float v2 = fmaxf(acc.z * inv + bi.z, 0.f);
    float v3 = fmaxf(acc.w * inv + bi.w, 0.f);
    v0 = (v0 - mm4.x) * rsqrtf(vv.x + BN_EPS) * gg.x + bb.x;
    v1 = (v1 - mm4.y) * rsqrtf(vv.y + BN_EPS) * gg.y + bb.y;
    v2 = (v2 - mm4.z) * rsqrtf(vv.z + BN_EPS) * gg.z + bb.z;
    v3 = (v3 - mm4.w) * rsqrtf(vv.w + BN_EPS) * gg.w + bb.w;
    unsigned long long o =
        (unsigned long long)f2bf(v0) |
        ((unsigned long long)f2bf(v1) << 16) |
        ((unsigned long long)f2bf(v2) << 32) |
        ((unsigned long long)f2bf(v3) << 48);
    __builtin_nontemporal_store(o, (unsigned long long*)&out16[(long long)d * FEAT + c0]);
}

// ===== fused head: mean-pool bf16 h2 + relu(pooled@lw1+lb1) @ lw2 + lb2 =====
__global__ __launch_bounds__(256) void head_fused(
    const unsigned short* __restrict__ h2, const int* __restrict__ batch,
    const float* __restrict__ lw1, const float* __restrict__ lb1,
    const float* __restrict__ lw2, const float* __restrict__ lb2,
    float* __restrict__ out) {
    int gph = blockIdx.x;
    int t = threadIdx.x;
    __shared__ float pooled[FEAT];
    __shared__ float zl[OUT_DIM];
    __shared__ int lo_s, hi_s;
    if (t == 0) {
        int lo = 0, hi = N_NODES;
        while (lo < hi) { int mid = (lo + hi) >> 1; if (batch[mid] < gph) lo = mid + 1; else hi = mid; }
        lo_s = lo;
        int lo2 = 0, hi2 = N_NODES;
        while (lo2 < hi2) { int mid = (lo2 + hi2) >> 1; if (batch[mid] < gph + 1) lo2 = mid + 1; else hi2 = mid; }
        hi_s = lo2;
    }
    __syncthreads();
    int lo = lo_s, hi = hi_s;
    float a0 = 0.f, a1 = 0.f, a2 = 0.f, a3 = 0.f;
    int n = lo;
    for (; n + 3 < hi; n += 4) {
        a0 += __uint_as_float((unsigned)h2[(long long)n * FEAT + t] << 16);
        a1 += __uint_as_float((unsigned)h2[(long long)(n + 1) * FEAT + t] << 16);
        a2 += __uint_as_float((unsigned)h2[(long long)(n + 2) * FEAT + t] << 16);
        a3 += __uint_as_float((unsigned)h2[(long long)(n + 3) * FEAT + t] << 16);
    }
    for (; n < hi; n++) a0 += __uint_as_float((unsigned)h2[(long long)n * FEAT + t] << 16);
    float cnt = fmaxf((float)(hi - lo), 1.f);
    pooled[t] = (a0 + a1 + a2 + a3) / cnt;
    __syncthreads();
    int j = t >> 1, kh = t & 1;
    float zp = 0.f;
    #pragma unroll 8
    for (int k = kh * 128; k < kh * 128 + 128; k++)
        zp += pooled[k] * lw1[k * OUT_DIM + j];
    zp += __shfl_xor(zp, 1);
    if (kh == 0) zl[j] = fmaxf(zp + lb1[j], 0.f);
    __syncthreads();
    int w = t >> 6, lane = t & 63;
    if (w < 2) {
        float p = zl[lane] * lw2[lane * 2 + w] + zl[lane + 64] * lw2[(lane + 64) * 2 + w];
        #pragma unroll
        for (int off = 1; off < 64; off <<= 1) p += __shfl_xor(p, off);
        if (lane == 0) out[gph * 2 + w] = p + lb2[w];
    }
}

extern "C" void kernel_launch(void* const* d_in, const int* in_sizes, int n_in,
                              void* d_out, int out_size, void* d_ws, size_t ws_size,
                              hipStream_t stream) {
    const float* x       = (const float*)d_in[0];
    const int*   ei      = (const int*)d_in[1];
    const int*   batch   = (const int*)d_in[2];
    const float* W1      = (const float*)d_in[3];
    const float* att_s1  = (const float*)d_in[4];
    const float* att_d1  = (const float*)d_in[5];
    const float* b1      = (const float*)d_in[6];
    const float* g1      = (const float*)d_in[7];
    const float* be1     = (const float*)d_in[8];
    const float* rm1     = (const float*)d_in[9];
    const float* rv1     = (const float*)d_in[10];
    const float* W2      = (const float*)d_in[11];
    const float* att_s2  = (const float*)d_in[12];
    const float* att_d2  = (const float*)d_in[13];
    const float* b2      = (const float*)d_in[14];
    const float* g2      = (const float*)d_in[15];
    const float* be2     = (const float*)d_in[16];
    const float* rm2     = (const float*)d_in[17];
    const float* rv2     = (const float*)d_in[18];
    const float* lw1     = (const float*)d_in[19];
    const float* lb1     = (const float*)d_in[20];
    const float* lw2     = (const float*)d_in[21];
    const float* lb2     = (const float*)d_in[22];
    float* out           = (float*)d_out;

    const int* src = ei;
    const int* dst = ei + N_EDGES;

    char* p = (char*)d_ws;
    auto carve = [&p](size_t bytes) -> void* {
        void* r = (void*)p;
        p += (bytes + 63) & ~(size_t)63;
        return r;
    };
    unsigned short* h2bf = (unsigned short*)carve(sizeof(short) * (size_t)N_NODES * FEAT);
    float* a_s    = (float*)carve(sizeof(float) * N_NODES * HEADS);
    float* a_d    = (float*)carve(sizeof(float) * N_NODES * HEADS);
    int*   deg    = (int*)carve(sizeof(int) * N_NODES);
    int*   ell    = (int*)carve(sizeof(int) * (size_t)N_NODES * ECAP);
    int*   ovf_cnt= (int*)carve(sizeof(int) * 16);
    int*   ovf    = (int*)carve(sizeof(int) * 2 * ET);
    unsigned char*  h8   = (unsigned char*)carve((size_t)M_PAD * FEAT);
    unsigned short* h1bf = (unsigned short*)carve(sizeof(short) * (size_t)M_PAD * FEAT);
    unsigned short* w1t  = (unsigned short*)carve(sizeof(short) * FEAT * F_IN);
    unsigned short* w2t  = (unsigned short*)carve(sizeof(short) * FEAT * FEAT);

    // ---- prep: weight transposes + deg/ovf zero + h1bf pad zero ----
    prep<<<((F_IN + FEAT) * 256 + 255) / 256, 256, 0, stream>>>(
        W1, W2, w1t, w2t, deg, ovf_cnt,
        (unsigned long long*)(h1bf + (size_t)N_NODES * FEAT));

    // ---- Layer 1 GEMM + ELL build in one heterogeneous launch ----
    gemm_mfma_gat<true, true><<<NBLK_GEMM + NBLK_BUILD, 256, 0, stream>>>(
        x, w1t, att_s1, att_d1, h8, a_s, a_d, F_IN,
        src, dst, deg, ell, ovf_cnt, ovf);
    gat_fused<<<N_NODES / 4, 256, 0, stream>>>(deg, ell, ovf_cnt, ovf, a_s, a_d, h8,
                                               b1, g1, be1, rm1, rv1, h1bf);

    // ---- Layer 2 ----
    gemm_mfma_gat<false, false><<<NBLK_GEMM, 256, 0, stream>>>(
        h1bf, w2t, att_s2, att_d2, h8, a_s, a_d, FEAT,
        nullptr, nullptr, nullptr, nullptr, nullptr, nullptr);
    gat_fused<<<N_NODES / 4, 256, 0, stream>>>(deg, ell, ovf_cnt, ovf, a_s, a_d, h8,
                                               b2, g2, be2, rm2, rv2, h2bf);

    // ---- fused head ----
    head_fused<<<NG, 256, 0, stream>>>(h2bf, batch, lw1, lb1, lw2, lb2, out);
}